// Round 3
// baseline (747.270 us; speedup 1.0000x reference)
//
#include <hip/hip_runtime.h>
#include <float.h>

#define M_TOT 16384
#define H_DIM 2048
#define NV    5000
#define NVP1  5001
#define N_PAD 5120
#define POOL_ROW_STRIDE (33 * 2048)
#define POOL_LAYER_OFF  (16 * 2048)

#define BM 256
#define BN 256
#define BK 64
#define NTM (M_TOT / BM)     // 64
#define NTN (N_PAD / BN)     // 20
#define NCHUNK (NTN * 4)     // 80 column-chunks of 64
#define MARGIN 0.03f

typedef __attribute__((ext_vector_type(8))) short short8;
typedef __attribute__((ext_vector_type(4))) float f32x4;

__device__ __forceinline__ void load16_to_lds(const void* g, void* l) {
    __builtin_amdgcn_global_load_lds((const __attribute__((address_space(1))) void*)g,
                                     (__attribute__((address_space(3))) void*)l, 16, 0, 0);
}

__device__ __forceinline__ unsigned short f2bf(float f) {
    unsigned u = __float_as_uint(f);
    return (unsigned short)((u + 0x7FFFu + ((u >> 16) & 1u)) >> 16);
}

// ---------------------------------------------------------------------------
// fp32 -> bf16 converts
// ---------------------------------------------------------------------------
__global__ __launch_bounds__(256) void conv_x_kernel(const float* __restrict__ x,
                                                     unsigned short* __restrict__ xbf) {
    const int stride = gridDim.x * blockDim.x;
    for (int i = blockIdx.x * blockDim.x + threadIdx.x; i < (M_TOT * H_DIM / 4); i += stride) {
        float4 v = ((const float4*)x)[i];
        ushort4 o = make_ushort4(f2bf(v.x), f2bf(v.y), f2bf(v.z), f2bf(v.w));
        ((ushort4*)xbf)[i] = o;
    }
}

__global__ __launch_bounds__(256) void conv_w_kernel(const float* __restrict__ gw,
                                                     unsigned short* __restrict__ wbf) {
    const int stride = gridDim.x * blockDim.x;
    for (int i = blockIdx.x * blockDim.x + threadIdx.x; i < (N_PAD * H_DIM / 4); i += stride) {
        const int row = i >> 9;
        ushort4 o = make_ushort4(0, 0, 0, 0);
        if (row < NVP1) {
            float4 v = ((const float4*)gw)[i];
            o = make_ushort4(f2bf(v.x), f2bf(v.y), f2bf(v.z), f2bf(v.w));
        }
        ((ushort4*)wbf)[i] = o;
    }
}

// ---------------------------------------------------------------------------
// 256x256 8-phase-style MFMA GEMM fused with per-64-col top-2 tracking.
// 8 waves (2M x 4N), BK=64, double-buffered 128KB LDS, counted vmcnt(8),
// raw s_barrier (no vmcnt-drain), setprio around MFMA, XOR-swizzled LDS via
// pre-swizzled global source (linear global_load_lds dest).
// ---------------------------------------------------------------------------
__global__ __launch_bounds__(512, 2)
void gemm_top2_kernel(const unsigned short* __restrict__ xbf,
                      const unsigned short* __restrict__ wbf,
                      const float* __restrict__ gb,
                      float* __restrict__ pv1, int* __restrict__ pi1,
                      float* __restrict__ pv2, int* __restrict__ pi2)
{
    __shared__ __align__(16) char albuf[2][BM * BK * 2];   // 2 x 32 KB
    __shared__ __align__(16) char blbuf[2][BN * BK * 2];   // 2 x 32 KB
    __shared__ float bl[BN];

    const int t    = threadIdx.x;
    const int w    = t >> 6;
    const int lane = t & 63;
    const int wm   = w >> 2;          // 0..1
    const int wn   = w & 3;           // 0..3

    // XCD-bijective swizzle: grid 1280 = 8 * 160
    const int bid0 = blockIdx.x;
    const int bid  = (bid0 & 7) * ((NTM * NTN) >> 3) + (bid0 >> 3);
    const int mt   = bid / NTN, nt = bid % NTN;
    const int m0   = mt * BM,   n0 = nt * BN;

    if (t < BN) bl[t] = (n0 + t < NVP1) ? gb[n0 + t] : 0.0f;

    // staging: per wave 4 A-insts + 4 B-insts, 8 rows each, linear LDS dest.
    // source pre-swizzled: slot = (lane&7) ^ (lane>>3)  (row%8 == lane>>3)
    const int srow = lane >> 3;
    const int slot = (lane & 7) ^ srow;
    const char* asrc[4]; const char* bsrc[4];
#pragma unroll
    for (int p = 0; p < 4; ++p) {
        const int r = w * 32 + p * 8 + srow;
        asrc[p] = (const char*)xbf + (size_t)(m0 + r) * (H_DIM * 2) + slot * 16;
        bsrc[p] = (const char*)wbf + (size_t)(n0 + r) * (H_DIM * 2) + slot * 16;
    }

    f32x4 acc[8][4];
    const f32x4 z4 = {0.f, 0.f, 0.f, 0.f};
#pragma unroll
    for (int i = 0; i < 8; ++i)
#pragma unroll
        for (int j = 0; j < 4; ++j) acc[i][j] = z4;

    // ds_read offsets: row = base + (lane&15), read slot = (kk*4 + lane>>4) ^ (lane&7)
    const int cl15 = lane & 15;
    const int kgrp = lane >> 4;
    int aoff[2], boff[2];
#pragma unroll
    for (int kk = 0; kk < 2; ++kk) {
        const int rs = ((kk * 4 + kgrp) ^ (lane & 7)) * 16;
        aoff[kk] = (wm * 128 + cl15) * 128 + rs;
        boff[kk] = (wn *  64 + cl15) * 128 + rs;
    }

    auto STAGE = [&](int kt, int buf) {
#pragma unroll
        for (int p = 0; p < 4; ++p) {
            load16_to_lds(asrc[p] + kt * (BK * 2), &albuf[buf][(w * 32 + p * 8) * 128]);
            load16_to_lds(bsrc[p] + kt * (BK * 2), &blbuf[buf][(w * 32 + p * 8) * 128]);
        }
    };

    STAGE(0, 0);

    for (int kt = 0; kt < H_DIM / BK; ++kt) {
        const int cur = kt & 1;
        // ---------------- Phase 0 ----------------
        if (kt < H_DIM / BK - 1) {
            STAGE(kt + 1, cur ^ 1);
            asm volatile("s_waitcnt vmcnt(8)" ::: "memory");   // tile kt landed; 8 in flight
        } else {
            asm volatile("s_waitcnt vmcnt(0)" ::: "memory");   // epilogue drain
        }
        __builtin_amdgcn_s_barrier();
        asm volatile("" ::: "memory");
        __builtin_amdgcn_sched_barrier(0);

        short8 bfr[4][2];
#pragma unroll
        for (int fj = 0; fj < 4; ++fj)
#pragma unroll
            for (int kk = 0; kk < 2; ++kk)
                bfr[fj][kk] = *(const short8*)(&blbuf[cur][fj * 2048 + boff[kk]]);
        {
            short8 af[2][2];
#pragma unroll
            for (int fi = 0; fi < 2; ++fi)
#pragma unroll
                for (int kk = 0; kk < 2; ++kk)
                    af[fi][kk] = *(const short8*)(&albuf[cur][fi * 2048 + aoff[kk]]);
            __builtin_amdgcn_s_setprio(1);
#pragma unroll
            for (int kk = 0; kk < 2; ++kk)
#pragma unroll
                for (int fi = 0; fi < 2; ++fi)
#pragma unroll
                    for (int fj = 0; fj < 4; ++fj)
                        acc[fi][fj] = __builtin_amdgcn_mfma_f32_16x16x32_bf16(af[fi][kk], bfr[fj][kk], acc[fi][fj], 0, 0, 0);
            __builtin_amdgcn_s_setprio(0);
        }
        __builtin_amdgcn_s_barrier();
        asm volatile("" ::: "memory");

        // ---------------- Phases 1..3 ----------------
#pragma unroll
        for (int ph = 1; ph < 4; ++ph) {
            short8 af[2][2];
#pragma unroll
            for (int fi = 0; fi < 2; ++fi)
#pragma unroll
                for (int kk = 0; kk < 2; ++kk)
                    af[fi][kk] = *(const short8*)(&albuf[cur][(ph * 2 + fi) * 2048 + aoff[kk]]);
            __builtin_amdgcn_s_setprio(1);
#pragma unroll
            for (int kk = 0; kk < 2; ++kk)
#pragma unroll
                for (int fi = 0; fi < 2; ++fi)
#pragma unroll
                    for (int fj = 0; fj < 4; ++fj)
                        acc[ph * 2 + fi][fj] = __builtin_amdgcn_mfma_f32_16x16x32_bf16(af[fi][kk], bfr[fj][kk], acc[ph * 2 + fi][fj], 0, 0, 0);
            __builtin_amdgcn_s_setprio(0);
            __builtin_amdgcn_s_barrier();
            asm volatile("" ::: "memory");
        }
    }

    // ---------------- Epilogue: top-2 per row over this wave's 64 cols ----------------
    const int g  = lane >> 4;
    const int cl = lane & 15;
    const int pc = nt * 4 + wn;
#pragma unroll
    for (int fi = 0; fi < 8; ++fi) {
#pragma unroll
        for (int q = 0; q < 4; ++q) {
            float v1 = -FLT_MAX, v2 = -FLT_MAX;
            int   i1 = 0x7fffffff, i2 = 0x7fffffff;
#pragma unroll
            for (int fj = 0; fj < 4; ++fj) {
                const int cin = wn * 64 + fj * 16 + cl;
                const int col = n0 + cin;
                float v = acc[fi][fj][q] + bl[cin];
                if (col >= NVP1) v = -FLT_MAX;
                if (v > v1 || (v == v1 && col < i1)) { v2 = v1; i2 = i1; v1 = v; i1 = col; }
                else if (v > v2 || (v == v2 && col < i2)) { v2 = v; i2 = col; }
            }
#pragma unroll
            for (int m = 1; m < 16; m <<= 1) {
                const float ov1 = __shfl_xor(v1, m, 64);
                const int   oi1 = __shfl_xor(i1, m, 64);
                const float ov2 = __shfl_xor(v2, m, 64);
                const int   oi2 = __shfl_xor(i2, m, 64);
                if (ov1 > v1 || (ov1 == v1 && oi1 < i1)) {
                    float nv2; int ni2;
                    if (v1 > ov2 || (v1 == ov2 && i1 < oi2)) { nv2 = v1; ni2 = i1; }
                    else                                     { nv2 = ov2; ni2 = oi2; }
                    v1 = ov1; i1 = oi1; v2 = nv2; i2 = ni2;
                } else {
                    if (ov1 > v2 || (ov1 == v2 && oi1 < i2)) { v2 = ov1; i2 = oi1; }
                }
            }
            if (cl == 0) {
                const int row = m0 + wm * 128 + fi * 16 + g * 4 + q;
                pv1[(size_t)pc * M_TOT + row] = v1;
                pi1[(size_t)pc * M_TOT + row] = i1;
                pv2[(size_t)pc * M_TOT + row] = v2;
                pi2[(size_t)pc * M_TOT + row] = i2;
            }
        }
    }
}

// ---------------------------------------------------------------------------
// Merge 80 chunk-partials per token; flag ambiguous tokens for fp32 rescore.
// ---------------------------------------------------------------------------
__device__ __forceinline__ void ins8(float v, int id, float tv[8], int ti[8]) {
#pragma unroll
    for (int s = 0; s < 8; ++s) {
        const bool b = (v > tv[s]) || (v == tv[s] && id < ti[s]);
        const float nv = b ? v : tv[s]; const int ni = b ? id : ti[s];
        v = b ? tv[s] : v; id = b ? ti[s] : id;
        tv[s] = nv; ti[s] = ni;
    }
}

__global__ __launch_bounds__(256)
void merge_kernel(const float* __restrict__ pv1, const int* __restrict__ pi1,
                  const float* __restrict__ pv2, const int* __restrict__ pi2,
                  int* __restrict__ fidx, int* __restrict__ counter, int* __restrict__ jobs)
{
    const int token = blockIdx.x * 256 + threadIdx.x;
    float tv[8]; int ti[8];
#pragma unroll
    for (int s = 0; s < 8; ++s) { tv[s] = -FLT_MAX; ti[s] = 0x7fffffff; }
    for (int pc = 0; pc < NCHUNK; ++pc) {
        ins8(pv1[(size_t)pc * M_TOT + token], pi1[(size_t)pc * M_TOT + token], tv, ti);
        ins8(pv2[(size_t)pc * M_TOT + token], pi2[(size_t)pc * M_TOT + token], tv, ti);
    }
    int cnt = 0;
#pragma unroll
    for (int s = 0; s < 8; ++s)
        if (ti[s] != 0x7fffffff && tv[s] >= tv[0] - MARGIN) cnt++;
    fidx[token] = ti[0];
    if (cnt > 1) {
        const int slot = atomicAdd(counter, 1);
        int* jp = jobs + (size_t)slot * 12;
        jp[0] = token;
        jp[1] = cnt;
#pragma unroll
        for (int s = 0; s < 8; ++s) jp[2 + s] = ti[s];
    }
}

// ---------------------------------------------------------------------------
// Exact fp32 rescore of candidate sets (<=8 dots per flagged token).
// ---------------------------------------------------------------------------
__global__ __launch_bounds__(256)
void rescore_kernel(const float* __restrict__ x, const float* __restrict__ gw,
                    const float* __restrict__ gb, const int* __restrict__ jobs,
                    const int* __restrict__ counter, int* __restrict__ fidx)
{
    __shared__ float sv[8];
    __shared__ int   si[8];
    __shared__ int   sjob[10];
    const int njobs = counter[0];
    const int t = threadIdx.x;
    for (int j = blockIdx.x; j < njobs; j += gridDim.x) {
        if (t < 10) sjob[t] = jobs[(size_t)j * 12 + t];
        __syncthreads();
        const int token = sjob[0];
        const int g  = t >> 5;
        const int sl = t & 31;
        const int cand = sjob[2 + g];
        float v = -FLT_MAX;
        if (cand <= NV) {
            const float4* xr = (const float4*)(x + (size_t)token * H_DIM);
            const float4* wr = (const float4*)(gw + (size_t)cand * H_DIM);
            float s = 0.f;
            for (int k = sl; k < H_DIM / 4; k += 32) {
                const float4 a = xr[k], b = wr[k];
                s = fmaf(a.x, b.x, s); s = fmaf(a.y, b.y, s);
                s = fmaf(a.z, b.z, s); s = fmaf(a.w, b.w, s);
            }
#pragma unroll
            for (int m = 1; m < 32; m <<= 1) s += __shfl_xor(s, m, 64);
            v = s + gb[cand];
        }
        if (sl == 0) { sv[g] = v; si[g] = (cand <= NV) ? cand : 0x7fffffff; }
        __syncthreads();
        if (t == 0) {
            float bv = sv[0]; int bi = si[0];
#pragma unroll
            for (int q = 1; q < 8; ++q)
                if (sv[q] > bv || (sv[q] == bv && si[q] < bi)) { bv = sv[q]; bi = si[q]; }
            fidx[token] = bi;
        }
        __syncthreads();
    }
}

// ---------------------------------------------------------------------------
// Final gather
// ---------------------------------------------------------------------------
__global__ __launch_bounds__(256)
void gather_kernel(const float* __restrict__ x, const float* __restrict__ pool,
                   const int* __restrict__ fidx, float* __restrict__ out)
{
    const int token = blockIdx.x;
    const int idx = fidx[token];
    const float4* src;
    if (idx == NV) {
        src = (const float4*)(x + (size_t)token * H_DIM);
    } else {
        const int safe = (idx < NV) ? idx : (NV - 1);
        src = (const float4*)(pool + (size_t)safe * POOL_ROW_STRIDE + POOL_LAYER_OFF);
    }
    float4* dst = (float4*)(out + (size_t)token * H_DIM);
    dst[threadIdx.x]       = src[threadIdx.x];
    dst[threadIdx.x + 256] = src[threadIdx.x + 256];
}

extern "C" void kernel_launch(void* const* d_in, const int* in_sizes, int n_in,
                              void* d_out, int out_size, void* d_ws, size_t ws_size,
                              hipStream_t stream)
{
    const float* x    = (const float*)d_in[0];
    const float* gw   = (const float*)d_in[1];
    const float* gb   = (const float*)d_in[2];
    const float* pool = (const float*)d_in[3];
    float* out = (float*)d_out;

    // x_bf parked in d_out (67 MB of 134 MB; gather fully overwrites d_out later)
    unsigned short* xbf = (unsigned short*)d_out;

    char* wsb = (char*)d_ws;
    unsigned short* wbf = (unsigned short*)wsb;
    size_t off = (size_t)N_PAD * H_DIM * 2;
    float* pv1 = (float*)(wsb + off); off += (size_t)NCHUNK * M_TOT * 4;
    int*   pi1 = (int*)  (wsb + off); off += (size_t)NCHUNK * M_TOT * 4;
    float* pv2 = (float*)(wsb + off); off += (size_t)NCHUNK * M_TOT * 4;
    int*   pi2 = (int*)  (wsb + off); off += (size_t)NCHUNK * M_TOT * 4;
    int*   fidx = (int*)(wsb + off);  off += (size_t)M_TOT * 4;
    int*   counter = (int*)(wsb + off); off += 256;
    int*   jobs = (int*)(wsb + off);

    hipMemsetAsync(counter, 0, sizeof(int), stream);

    conv_x_kernel<<<4096, 256, 0, stream>>>(x, xbf);
    conv_w_kernel<<<2560, 256, 0, stream>>>(gw, wbf);

    gemm_top2_kernel<<<NTM * NTN, 512, 0, stream>>>(xbf, wbf, gb, pv1, pi1, pv2, pi2);

    merge_kernel<<<M_TOT / 256, 256, 0, stream>>>(pv1, pi1, pv2, pi2, fidx, counter, jobs);
    rescore_kernel<<<256, 256, 0, stream>>>(x, gw, gb, jobs, counter, fidx);
    gather_kernel<<<M_TOT, 256, 0, stream>>>(x, pool, fidx, out);
}

// Round 4
// 537.989 us; speedup vs baseline: 1.3890x; 1.3890x over previous
//
#include <hip/hip_runtime.h>
#include <float.h>

#define M_TOT 16384
#define H_DIM 2048
#define NV    5000
#define NVP1  5001
#define N_PAD 5120
#define POOL_ROW_STRIDE (33 * 2048)
#define POOL_LAYER_OFF  (16 * 2048)

#define BM 128
#define BN 128
#define BK 64
#define NTM (M_TOT / BM)       // 128
#define NTN (N_PAD / BN)       // 40
#define NWG (NTM * NTN)        // 5120 (divisible by 8)
#define NCHUNK (NTN * 2)       // 80 column-chunks of 64
#define MARGIN 0.03f

typedef __attribute__((ext_vector_type(8))) short short8;
typedef __attribute__((ext_vector_type(4))) float f32x4;
typedef unsigned long long ull;

__device__ __forceinline__ void load16_to_lds(const void* g, void* l) {
    __builtin_amdgcn_global_load_lds((const __attribute__((address_space(1))) void*)g,
                                     (__attribute__((address_space(3))) void*)l, 16, 0, 0);
}

__device__ __forceinline__ unsigned short f2bf(float f) {
    unsigned u = __float_as_uint(f);
    return (unsigned short)((u + 0x7FFFu + ((u >> 16) & 1u)) >> 16);
}

// sortable u64 key: high 32 = monotone-mapped float, low 32 = ~col (lower col wins ties)
__device__ __forceinline__ int key_col(ull k) { return (int)(~(unsigned)(k & 0xffffffffu)); }
__device__ __forceinline__ float key_val(ull k) {
    unsigned kk = (unsigned)(k >> 32);
    unsigned u = (kk & 0x80000000u) ? (kk ^ 0x80000000u) : ~kk;
    return __uint_as_float(u);
}

// ---------------------------------------------------------------------------
// fused fp32 -> bf16 converts (x and zero-padded gate_w)
// ---------------------------------------------------------------------------
#define XCNT (M_TOT * H_DIM / 4)
#define WCNT (N_PAD * H_DIM / 4)
__global__ __launch_bounds__(256) void conv_kernel(const float* __restrict__ x,
                                                   const float* __restrict__ gw,
                                                   unsigned short* __restrict__ xbf,
                                                   unsigned short* __restrict__ wbf) {
    const int stride = gridDim.x * blockDim.x;
    for (int i = blockIdx.x * blockDim.x + threadIdx.x; i < XCNT + WCNT; i += stride) {
        if (i < XCNT) {
            float4 v = ((const float4*)x)[i];
            ((ushort4*)xbf)[i] = make_ushort4(f2bf(v.x), f2bf(v.y), f2bf(v.z), f2bf(v.w));
        } else {
            const int j = i - XCNT;
            const int row = j >> 9;
            ushort4 o = make_ushort4(0, 0, 0, 0);
            if (row < NVP1) {
                float4 v = ((const float4*)gw)[j];
                o = make_ushort4(f2bf(v.x), f2bf(v.y), f2bf(v.z), f2bf(v.w));
            }
            ((ushort4*)wbf)[j] = o;
        }
    }
}

// ---------------------------------------------------------------------------
// MFMA bf16 GEMM (x_bf @ gw_bf^T) fused with per-64-col-chunk top-2 tracking.
// R2-proven structure: 128x128 tile, BK=64, 4 waves (2x2), XOR-swizzled LDS
// via pre-swizzled global source. New: 3 blocks/CU, XCD swizzle, u64-packed
// top-2 epilogue.
// ---------------------------------------------------------------------------
__global__ __launch_bounds__(256, 3)
void gemm_top2_kernel(const unsigned short* __restrict__ xbf,
                      const unsigned short* __restrict__ wbf,
                      const float* __restrict__ gb,
                      ull* __restrict__ pk1, ull* __restrict__ pk2)
{
    __shared__ __align__(16) char albuf[BM * BK * 2];   // 16 KB, row stride 128B
    __shared__ __align__(16) char blbuf[BN * BK * 2];   // 16 KB
    __shared__ float bl[BN];

    const int t    = threadIdx.x;
    const int w    = t >> 6;
    const int lane = t & 63;
    const int wm   = w >> 1;
    const int wn   = w & 1;

    // XCD-bijective swizzle: 5120 = 8 * 640
    const int bid0 = blockIdx.x;
    const int bid  = (bid0 & 7) * (NWG >> 3) + (bid0 >> 3);
    const int nt   = bid % NTN;
    const int mt   = bid / NTN;
    const int m0   = mt * BM;
    const int n0   = nt * BN;

    if (t < BN) bl[t] = (n0 + t < NVP1) ? gb[n0 + t] : 0.0f;

    // staging pointers: wave w covers rows w*32..w*32+31 (4 insts x 8 rows),
    // global source pre-swizzled so linear LDS dest yields swizzled layout
    const int srow  = lane >> 3;
    const int sslot = lane & 7;
    const char* agp[4];
    const char* bgp[4];
#pragma unroll
    for (int p = 0; p < 4; ++p) {
        const int r = w * 32 + p * 8 + srow;
        agp[p] = (const char*)xbf + (size_t)(m0 + r) * (H_DIM * 2) + ((sslot ^ (r & 7)) << 4);
        bgp[p] = (const char*)wbf + (size_t)(n0 + r) * (H_DIM * 2) + ((sslot ^ (r & 7)) << 4);
    }

    f32x4 acc[4][4];
    const f32x4 zero4 = {0.f, 0.f, 0.f, 0.f};
#pragma unroll
    for (int i = 0; i < 4; ++i)
#pragma unroll
        for (int j = 0; j < 4; ++j) acc[i][j] = zero4;

    for (int kt = 0; kt < H_DIM / BK; ++kt) {
        __syncthreads();
#pragma unroll
        for (int p = 0; p < 4; ++p) {
            load16_to_lds(agp[p] + kt * (BK * 2), albuf + w * 4096 + p * 1024);
            load16_to_lds(bgp[p] + kt * (BK * 2), blbuf + w * 4096 + p * 1024);
        }
        __syncthreads();

#pragma unroll
        for (int kk = 0; kk < 2; ++kk) {
            short8 af[4], bfr[4];
#pragma unroll
            for (int f = 0; f < 4; ++f) {
                const int ra = wm * 64 + f * 16 + (lane & 15);
                const int sa = (kk * 4 + (lane >> 4)) ^ (ra & 7);
                af[f] = *(const short8*)(albuf + ra * 128 + sa * 16);
                const int rb = wn * 64 + f * 16 + (lane & 15);
                const int sb = (kk * 4 + (lane >> 4)) ^ (rb & 7);
                bfr[f] = *(const short8*)(blbuf + rb * 128 + sb * 16);
            }
#pragma unroll
            for (int i = 0; i < 4; ++i)
#pragma unroll
                for (int j = 0; j < 4; ++j)
                    acc[i][j] = __builtin_amdgcn_mfma_f32_16x16x32_bf16(af[i], bfr[j], acc[i][j], 0, 0, 0);
        }
    }

    // Epilogue: u64-packed top-2 per row, 16-lane shuffle reduce.
    const int g  = lane >> 4;
    const int cl = lane & 15;
    const int pc = nt * 2 + wn;
#pragma unroll
    for (int fi = 0; fi < 4; ++fi) {
#pragma unroll
        for (int q = 0; q < 4; ++q) {
            ull k1 = 0, k2 = 0;
#pragma unroll
            for (int fj = 0; fj < 4; ++fj) {
                const int cin = wn * 64 + fj * 16 + cl;
                const int col = n0 + cin;
                const float v = acc[fi][fj][q] + bl[cin];
                unsigned u = __float_as_uint(v);
                unsigned k32 = u ^ ((u >> 31) ? 0xFFFFFFFFu : 0x80000000u);
                int ecol = col;
                if (col >= NVP1) { k32 = 0u; ecol = 0x7fffffff; }
                const ull k = ((ull)k32 << 32) | (unsigned)(~ecol);
                const bool a = k > k1;
                const ull nk2 = a ? k1 : (k > k2 ? k : k2);
                k1 = a ? k : k1;
                k2 = nk2;
            }
#pragma unroll
            for (int m = 1; m < 16; m <<= 1) {
                const ull o1 = __shfl_xor(k1, m, 64);
                const ull o2 = __shfl_xor(k2, m, 64);
                const bool a = k1 >= o1;
                const ull n2 = a ? (k2 >= o1 ? k2 : o1) : (o2 >= k1 ? o2 : k1);
                k1 = a ? k1 : o1;
                k2 = n2;
            }
            if (cl == 0) {
                const int row = m0 + wm * 64 + fi * 16 + g * 4 + q;
                pk1[(size_t)pc * M_TOT + row] = k1;
                pk2[(size_t)pc * M_TOT + row] = k2;
            }
        }
    }
}

// ---------------------------------------------------------------------------
// Merge 80 chunk-partials (u64 keys); flag ambiguous tokens for fp32 rescore.
// ---------------------------------------------------------------------------
__device__ __forceinline__ void ins8k(ull k, ull tk[8]) {
#pragma unroll
    for (int s = 0; s < 8; ++s) {
        const bool b = k > tk[s];
        const ull nv = b ? k : tk[s];
        k = b ? tk[s] : k;
        tk[s] = nv;
    }
}

__global__ __launch_bounds__(256)
void merge_kernel(const ull* __restrict__ pk1, const ull* __restrict__ pk2,
                  int* __restrict__ fidx, int* __restrict__ counter, int* __restrict__ jobs)
{
    const int token = blockIdx.x * 256 + threadIdx.x;
    ull tk[8];
#pragma unroll
    for (int s = 0; s < 8; ++s) tk[s] = 0;
    for (int pc = 0; pc < NCHUNK; ++pc) {
        ins8k(pk1[(size_t)pc * M_TOT + token], tk);
        ins8k(pk2[(size_t)pc * M_TOT + token], tk);
    }
    const float v0 = key_val(tk[0]);
    int cols[8];
    int cnt = 0;
#pragma unroll
    for (int s = 0; s < 8; ++s) {
        int c = key_col(tk[s]);
        if ((unsigned)c > (unsigned)NV) c = 0x7fffffff;          // invalid/masked/empty
        else if (!(key_val(tk[s]) >= v0 - MARGIN)) c = 0x7fffffff; // outside margin
        cols[s] = c;
        if (c != 0x7fffffff) cnt++;
    }
    fidx[token] = key_col(tk[0]);
    if (cnt > 1) {
        const int slot = atomicAdd(counter, 1);
        int* jp = jobs + (size_t)slot * 12;
        jp[0] = token;
        jp[1] = cnt;
#pragma unroll
        for (int s = 0; s < 8; ++s) jp[2 + s] = cols[s];
    }
}

// ---------------------------------------------------------------------------
// Exact fp32 rescore of candidate sets (<=8 dots per flagged token).
// ---------------------------------------------------------------------------
__global__ __launch_bounds__(256)
void rescore_kernel(const float* __restrict__ x, const float* __restrict__ gw,
                    const float* __restrict__ gb, const int* __restrict__ jobs,
                    const int* __restrict__ counter, int* __restrict__ fidx)
{
    __shared__ float sv[8];
    __shared__ int   si[8];
    __shared__ int   sjob[10];
    const int njobs = counter[0];
    const int t = threadIdx.x;
    for (int j = blockIdx.x; j < njobs; j += gridDim.x) {
        if (t < 10) sjob[t] = jobs[(size_t)j * 12 + t];
        __syncthreads();
        const int token = sjob[0];
        const int g  = t >> 5;
        const int sl = t & 31;
        const int cand = sjob[2 + g];
        float v = -FLT_MAX;
        if (cand <= NV) {
            const float4* xr = (const float4*)(x + (size_t)token * H_DIM);
            const float4* wr = (const float4*)(gw + (size_t)cand * H_DIM);
            float s = 0.f;
            for (int k = sl; k < H_DIM / 4; k += 32) {
                const float4 a = xr[k], b = wr[k];
                s = fmaf(a.x, b.x, s); s = fmaf(a.y, b.y, s);
                s = fmaf(a.z, b.z, s); s = fmaf(a.w, b.w, s);
            }
#pragma unroll
            for (int m = 1; m < 32; m <<= 1) s += __shfl_xor(s, m, 64);
            v = s + gb[cand];
        }
        if (sl == 0) { sv[g] = v; si[g] = (cand <= NV) ? cand : 0x7fffffff; }
        __syncthreads();
        if (t == 0) {
            float bv = sv[0]; int bi = si[0];
#pragma unroll
            for (int q = 1; q < 8; ++q)
                if (sv[q] > bv || (sv[q] == bv && si[q] < bi)) { bv = sv[q]; bi = si[q]; }
            fidx[token] = bi;
        }
        __syncthreads();
    }
}

// ---------------------------------------------------------------------------
// Final gather
// ---------------------------------------------------------------------------
__global__ __launch_bounds__(256)
void gather_kernel(const float* __restrict__ x, const float* __restrict__ pool,
                   const int* __restrict__ fidx, float* __restrict__ out)
{
    const int token = blockIdx.x;
    const int idx = fidx[token];
    const float4* src;
    if (idx == NV) {
        src = (const float4*)(x + (size_t)token * H_DIM);
    } else {
        const int safe = (idx < NV) ? idx : (NV - 1);
        src = (const float4*)(pool + (size_t)safe * POOL_ROW_STRIDE + POOL_LAYER_OFF);
    }
    float4* dst = (float4*)(out + (size_t)token * H_DIM);
    dst[threadIdx.x]       = src[threadIdx.x];
    dst[threadIdx.x + 256] = src[threadIdx.x + 256];
}

extern "C" void kernel_launch(void* const* d_in, const int* in_sizes, int n_in,
                              void* d_out, int out_size, void* d_ws, size_t ws_size,
                              hipStream_t stream)
{
    const float* x    = (const float*)d_in[0];
    const float* gw   = (const float*)d_in[1];
    const float* gb   = (const float*)d_in[2];
    const float* pool = (const float*)d_in[3];
    float* out = (float*)d_out;

    // x_bf parked in d_out (67 MB of 134 MB; gather fully overwrites d_out later)
    unsigned short* xbf = (unsigned short*)d_out;

    char* wsb = (char*)d_ws;
    unsigned short* wbf = (unsigned short*)wsb;                   // 20.97 MB
    size_t off = (size_t)N_PAD * H_DIM * 2;
    ull* pk1 = (ull*)(wsb + off); off += (size_t)NCHUNK * M_TOT * 8;   // 10.5 MB
    ull* pk2 = (ull*)(wsb + off); off += (size_t)NCHUNK * M_TOT * 8;   // 10.5 MB
    int* fidx = (int*)(wsb + off); off += (size_t)M_TOT * 4;
    int* counter = (int*)(wsb + off); off += 256;
    int* jobs = (int*)(wsb + off);                                 // 768 KB

    hipMemsetAsync(counter, 0, sizeof(int), stream);

    conv_kernel<<<3072, 256, 0, stream>>>(x, gw, xbf, wbf);

    gemm_top2_kernel<<<NWG, 256, 0, stream>>>(xbf, wbf, gb, pk1, pk2);

    merge_kernel<<<M_TOT / 256, 256, 0, stream>>>(pk1, pk2, fidx, counter, jobs);
    rescore_kernel<<<256, 256, 0, stream>>>(x, gw, gb, jobs, counter, fidx);
    gather_kernel<<<M_TOT, 256, 0, stream>>>(x, pool, fidx, out);
}

// Round 5
// 483.937 us; speedup vs baseline: 1.5441x; 1.1117x over previous
//
#include <hip/hip_runtime.h>
#include <float.h>

#define M_TOT 16384
#define H_DIM 2048
#define NV    5000
#define NVP1  5001
#define N_PAD 5120
#define POOL_ROW_STRIDE (33 * 2048)
#define POOL_LAYER_OFF  (16 * 2048)

#define BM 128
#define BN 128
#define BKB 128                 // K-tile in BYTES per row (=128 int8 elems)
#define KITER (H_DIM / 128)     // 16
#define NTM (M_TOT / BM)        // 128
#define NTN (N_PAD / BN)        // 40
#define NWG (NTM * NTN)         // 5120 (divisible by 8)
#define NCHUNK (NTN * 2)        // 80 column-chunks of 64
#define MARGIN 0.2f

#define XMAX 6.0f
#define WMAX 0.12f
#define SF   ((XMAX / 127.0f) * (WMAX / 127.0f))

typedef __attribute__((ext_vector_type(4))) int i32x4;
typedef unsigned long long ull;

__device__ __forceinline__ void load16_to_lds(const void* g, void* l) {
    __builtin_amdgcn_global_load_lds((const __attribute__((address_space(1))) void*)g,
                                     (__attribute__((address_space(3))) void*)l, 16, 0, 0);
}

__device__ __forceinline__ int q127(float v, float inv_step, float vmax) {
    float c = fminf(fmaxf(v, -vmax), vmax);
    return (int)rintf(c * inv_step);
}

// sortable u64 key: high 32 = monotone-mapped float, low 32 = ~col (lower col wins ties)
__device__ __forceinline__ int key_col(ull k) { return (int)(~(unsigned)(k & 0xffffffffu)); }
__device__ __forceinline__ float key_val(ull k) {
    unsigned kk = (unsigned)(k >> 32);
    unsigned u = (kk & 0x80000000u) ? (kk ^ 0x80000000u) : ~kk;
    return __uint_as_float(u);
}

// ---------------------------------------------------------------------------
// fused fp32 -> int8 quantize (x clamp +-6, w clamp +-0.12, zero-padded)
// ---------------------------------------------------------------------------
#define XCNT (M_TOT * H_DIM / 4)
#define WCNT (N_PAD * H_DIM / 4)
__global__ __launch_bounds__(256) void quant_kernel(const float* __restrict__ x,
                                                    const float* __restrict__ gw,
                                                    unsigned* __restrict__ xq,   // 4 int8 packed
                                                    unsigned* __restrict__ wq) {
    const int stride = gridDim.x * blockDim.x;
    const float xinv = 127.0f / XMAX;
    const float winv = 127.0f / WMAX;
    for (int i = blockIdx.x * blockDim.x + threadIdx.x; i < XCNT + WCNT; i += stride) {
        if (i < XCNT) {
            float4 v = ((const float4*)x)[i];
            unsigned p = ((unsigned)(q127(v.x, xinv, XMAX) & 0xff)) |
                         ((unsigned)(q127(v.y, xinv, XMAX) & 0xff) << 8) |
                         ((unsigned)(q127(v.z, xinv, XMAX) & 0xff) << 16) |
                         ((unsigned)(q127(v.w, xinv, XMAX) & 0xff) << 24);
            xq[i] = p;
        } else {
            const int j = i - XCNT;
            const int row = j >> 9;               // 512 float4 per row
            unsigned p = 0;
            if (row < NVP1) {
                float4 v = ((const float4*)gw)[j];
                p = ((unsigned)(q127(v.x, winv, WMAX) & 0xff)) |
                    ((unsigned)(q127(v.y, winv, WMAX) & 0xff) << 8) |
                    ((unsigned)(q127(v.z, winv, WMAX) & 0xff) << 16) |
                    ((unsigned)(q127(v.w, winv, WMAX) & 0xff) << 24);
            }
            wq[j] = p;
        }
    }
}

// ---------------------------------------------------------------------------
// int8 MFMA GEMM (xq @ wq^T, exact i32 accum) fused with per-64-col top-3.
// Identical byte-structure to the proven bf16 kernel: 128x128 tile, 128-B
// K-rows (=128 i8), 4 waves (2x2), XOR-swizzled LDS via pre-swizzled global
// source, 16 K-iterations.
// ---------------------------------------------------------------------------
__global__ __launch_bounds__(256, 3)
void gemm_top3_kernel(const unsigned char* __restrict__ xq,
                      const unsigned char* __restrict__ wq,
                      const float* __restrict__ gb,
                      ull* __restrict__ pk1, ull* __restrict__ pk2, ull* __restrict__ pk3)
{
    __shared__ __align__(16) char albuf[BM * BKB];   // 16 KB, row stride 128B
    __shared__ __align__(16) char blbuf[BN * BKB];   // 16 KB
    __shared__ float bl[BN];

    const int t    = threadIdx.x;
    const int w    = t >> 6;
    const int lane = t & 63;
    const int wm   = w >> 1;
    const int wn   = w & 1;

    // XCD-bijective swizzle: 5120 = 8 * 640
    const int bid0 = blockIdx.x;
    const int bid  = (bid0 & 7) * (NWG >> 3) + (bid0 >> 3);
    const int nt   = bid % NTN;
    const int mt   = bid / NTN;
    const int m0   = mt * BM;
    const int n0   = nt * BN;

    if (t < BN) bl[t] = (n0 + t < NVP1) ? gb[n0 + t] : 0.0f;

    // staging pointers: wave w covers rows w*32..w*32+31 (4 insts x 8 rows),
    // global source pre-swizzled so linear LDS dest yields swizzled layout
    const int srow  = lane >> 3;
    const int sslot = lane & 7;
    const char* agp[4];
    const char* bgp[4];
#pragma unroll
    for (int p = 0; p < 4; ++p) {
        const int r = w * 32 + p * 8 + srow;
        agp[p] = (const char*)xq + (size_t)(m0 + r) * H_DIM + ((sslot ^ (r & 7)) << 4);
        bgp[p] = (const char*)wq + (size_t)(n0 + r) * H_DIM + ((sslot ^ (r & 7)) << 4);
    }

    i32x4 acc[4][4];
    const i32x4 z4 = {0, 0, 0, 0};
#pragma unroll
    for (int i = 0; i < 4; ++i)
#pragma unroll
        for (int j = 0; j < 4; ++j) acc[i][j] = z4;

    for (int kt = 0; kt < KITER; ++kt) {
        __syncthreads();
#pragma unroll
        for (int p = 0; p < 4; ++p) {
            load16_to_lds(agp[p] + kt * BKB, albuf + w * 4096 + p * 1024);
            load16_to_lds(bgp[p] + kt * BKB, blbuf + w * 4096 + p * 1024);
        }
        __syncthreads();

#pragma unroll
        for (int kk = 0; kk < 2; ++kk) {
            i32x4 af[4], bfr[4];
#pragma unroll
            for (int f = 0; f < 4; ++f) {
                const int ra = wm * 64 + f * 16 + (lane & 15);
                const int sa = (kk * 4 + (lane >> 4)) ^ (ra & 7);
                af[f] = *(const i32x4*)(albuf + ra * 128 + sa * 16);
                const int rb = wn * 64 + f * 16 + (lane & 15);
                const int sb = (kk * 4 + (lane >> 4)) ^ (rb & 7);
                bfr[f] = *(const i32x4*)(blbuf + rb * 128 + sb * 16);
            }
#pragma unroll
            for (int i = 0; i < 4; ++i)
#pragma unroll
                for (int j = 0; j < 4; ++j)
                    acc[i][j] = __builtin_amdgcn_mfma_i32_16x16x64_i8(af[i], bfr[j], acc[i][j], 0, 0, 0);
        }
    }

    // Epilogue: u64-packed top-3 per row, 16-lane shuffle reduce.
    const int g  = lane >> 4;
    const int cl = lane & 15;
    const int pc = nt * 2 + wn;
#pragma unroll
    for (int fi = 0; fi < 4; ++fi) {
#pragma unroll
        for (int q = 0; q < 4; ++q) {
            ull k1 = 0, k2 = 0, k3 = 0;
#pragma unroll
            for (int fj = 0; fj < 4; ++fj) {
                const int cin = wn * 64 + fj * 16 + cl;
                const int col = n0 + cin;
                const float v = (float)acc[fi][fj][q] * SF + bl[cin];
                unsigned u = __float_as_uint(v);
                unsigned k32 = u ^ ((u >> 31) ? 0xFFFFFFFFu : 0x80000000u);
                int ecol = col;
                if (col >= NVP1) { k32 = 0u; ecol = 0x7fffffff; }
                const ull k = ((ull)k32 << 32) | (unsigned)(~ecol);
                if (k > k1)      { k3 = k2; k2 = k1; k1 = k; }
                else if (k > k2) { k3 = k2; k2 = k; }
                else if (k > k3) { k3 = k; }
            }
#pragma unroll
            for (int m = 1; m < 16; m <<= 1) {
                const ull o1 = __shfl_xor(k1, m, 64);
                const ull o2 = __shfl_xor(k2, m, 64);
                const ull o3 = __shfl_xor(k3, m, 64);
                // merge two sorted triples -> top-3
                const bool a = k1 >= o1;
                const ull w2 = a ? k2 : o2, w3 = a ? k3 : o3;
                const ull l1 = a ? o1 : k1, l2 = a ? o2 : k2;
                const bool b = w2 >= l1;
                const ull n1 = a ? k1 : o1;
                const ull n2 = b ? w2 : l1;
                const ull n3 = b ? (w3 >= l1 ? w3 : l1) : (w2 >= l2 ? w2 : l2);
                k1 = n1; k2 = n2; k3 = n3;
            }
            if (cl == 0) {
                const int row = m0 + wm * 64 + fi * 16 + g * 4 + q;
                pk1[(size_t)pc * M_TOT + row] = k1;
                pk2[(size_t)pc * M_TOT + row] = k2;
                pk3[(size_t)pc * M_TOT + row] = k3;
            }
        }
    }
}

// ---------------------------------------------------------------------------
// Merge 80 chunk-partials (3 u64 keys each); flag ambiguous tokens.
// ---------------------------------------------------------------------------
__device__ __forceinline__ void ins8k(ull k, ull tk[8]) {
#pragma unroll
    for (int s = 0; s < 8; ++s) {
        const bool b = k > tk[s];
        const ull nv = b ? k : tk[s];
        k = b ? tk[s] : k;
        tk[s] = nv;
    }
}

__global__ __launch_bounds__(256)
void merge_kernel(const ull* __restrict__ pk1, const ull* __restrict__ pk2,
                  const ull* __restrict__ pk3,
                  int* __restrict__ fidx, int* __restrict__ counter, int* __restrict__ jobs)
{
    const int token = blockIdx.x * 256 + threadIdx.x;
    ull tk[8];
#pragma unroll
    for (int s = 0; s < 8; ++s) tk[s] = 0;
    for (int pc = 0; pc < NCHUNK; ++pc) {
        ins8k(pk1[(size_t)pc * M_TOT + token], tk);
        ins8k(pk2[(size_t)pc * M_TOT + token], tk);
        ins8k(pk3[(size_t)pc * M_TOT + token], tk);
    }
    const float v0 = key_val(tk[0]);
    int cols[8];
    int cnt = 0;
#pragma unroll
    for (int s = 0; s < 8; ++s) {
        int c = key_col(tk[s]);
        if ((unsigned)c > (unsigned)NV) c = 0x7fffffff;            // invalid/masked/empty
        else if (!(key_val(tk[s]) >= v0 - MARGIN)) c = 0x7fffffff; // outside margin
        cols[s] = c;
        if (c != 0x7fffffff) cnt++;
    }
    fidx[token] = key_col(tk[0]);
    if (cnt > 1) {
        const int slot = atomicAdd(counter, 1);
        int* jp = jobs + (size_t)slot * 12;
        jp[0] = token;
        jp[1] = cnt;
#pragma unroll
        for (int s = 0; s < 8; ++s) jp[2 + s] = cols[s];
    }
}

// ---------------------------------------------------------------------------
// Exact fp32 rescore of candidate sets (<=8 dots per flagged token).
// ---------------------------------------------------------------------------
__global__ __launch_bounds__(256)
void rescore_kernel(const float* __restrict__ x, const float* __restrict__ gw,
                    const float* __restrict__ gb, const int* __restrict__ jobs,
                    const int* __restrict__ counter, int* __restrict__ fidx)
{
    __shared__ float sv[8];
    __shared__ int   si[8];
    __shared__ int   sjob[10];
    const int njobs = counter[0];
    const int t = threadIdx.x;
    for (int j = blockIdx.x; j < njobs; j += gridDim.x) {
        if (t < 10) sjob[t] = jobs[(size_t)j * 12 + t];
        __syncthreads();
        const int token = sjob[0];
        const int g  = t >> 5;
        const int sl = t & 31;
        const int cand = sjob[2 + g];
        float v = -FLT_MAX;
        if (cand <= NV) {
            const float4* xr = (const float4*)(x + (size_t)token * H_DIM);
            const float4* wr = (const float4*)(gw + (size_t)cand * H_DIM);
            float s = 0.f;
            for (int k = sl; k < H_DIM / 4; k += 32) {
                const float4 a = xr[k], b = wr[k];
                s = fmaf(a.x, b.x, s); s = fmaf(a.y, b.y, s);
                s = fmaf(a.z, b.z, s); s = fmaf(a.w, b.w, s);
            }
#pragma unroll
            for (int m = 1; m < 32; m <<= 1) s += __shfl_xor(s, m, 64);
            v = s + gb[cand];
        }
        if (sl == 0) { sv[g] = v; si[g] = (cand <= NV) ? cand : 0x7fffffff; }
        __syncthreads();
        if (t == 0) {
            float bv = sv[0]; int bi = si[0];
#pragma unroll
            for (int q = 1; q < 8; ++q)
                if (sv[q] > bv || (sv[q] == bv && si[q] < bi)) { bv = sv[q]; bi = si[q]; }
            fidx[token] = bi;
        }
        __syncthreads();
    }
}

// ---------------------------------------------------------------------------
// Final gather
// ---------------------------------------------------------------------------
__global__ __launch_bounds__(256)
void gather_kernel(const float* __restrict__ x, const float* __restrict__ pool,
                   const int* __restrict__ fidx, float* __restrict__ out)
{
    const int token = blockIdx.x;
    const int idx = fidx[token];
    const float4* src;
    if (idx == NV) {
        src = (const float4*)(x + (size_t)token * H_DIM);
    } else {
        const int safe = (idx < NV) ? idx : (NV - 1);
        src = (const float4*)(pool + (size_t)safe * POOL_ROW_STRIDE + POOL_LAYER_OFF);
    }
    float4* dst = (float4*)(out + (size_t)token * H_DIM);
    dst[threadIdx.x]       = src[threadIdx.x];
    dst[threadIdx.x + 256] = src[threadIdx.x + 256];
}

extern "C" void kernel_launch(void* const* d_in, const int* in_sizes, int n_in,
                              void* d_out, int out_size, void* d_ws, size_t ws_size,
                              hipStream_t stream)
{
    const float* x    = (const float*)d_in[0];
    const float* gw   = (const float*)d_in[1];
    const float* gb   = (const float*)d_in[2];
    const float* pool = (const float*)d_in[3];
    float* out = (float*)d_out;

    // x_q parked in d_out (33.5 MB of 134 MB; gather fully overwrites d_out later)
    unsigned char* xq = (unsigned char*)d_out;

    char* wsb = (char*)d_ws;
    unsigned char* wq = (unsigned char*)wsb;                           // 10.5 MB
    size_t off = (size_t)N_PAD * H_DIM;
    ull* pk1 = (ull*)(wsb + off); off += (size_t)NCHUNK * M_TOT * 8;   // 10.5 MB
    ull* pk2 = (ull*)(wsb + off); off += (size_t)NCHUNK * M_TOT * 8;   // 10.5 MB
    ull* pk3 = (ull*)(wsb + off); off += (size_t)NCHUNK * M_TOT * 8;   // 10.5 MB
    int* fidx = (int*)(wsb + off); off += (size_t)M_TOT * 4;
    int* counter = (int*)(wsb + off); off += 256;
    int* jobs = (int*)(wsb + off);                                     // 768 KB

    hipMemsetAsync(counter, 0, sizeof(int), stream);

    quant_kernel<<<3072, 256, 0, stream>>>(x, gw, (unsigned*)xq, (unsigned*)wq);

    gemm_top3_kernel<<<NWG, 256, 0, stream>>>(xq, wq, gb, pk1, pk2, pk3);

    merge_kernel<<<M_TOT / 256, 256, 0, stream>>>(pk1, pk2, pk3, fidx, counter, jobs);
    rescore_kernel<<<512, 256, 0, stream>>>(x, gw, gb, jobs, counter, fidx);
    gather_kernel<<<M_TOT, 256, 0, stream>>>(x, pool, fidx, out);
}